// Round 2
// baseline (318.105 us; speedup 1.0000x reference)
//
#include <hip/hip_runtime.h>

// IoULoss, C=4. counts: inter[c], cnt_pred[c], cnt_label[c]; union = cp+cl-inter.
// 134 MB read, ~half L3-resident after harness restore -> latency-bound, not BW.
// R2: 2048 blocks (32 waves/CU), unroll x4 (8 loads in flight), fused finalize.

#define NCLS 4

__global__ __launch_bounds__(256) void iou_fused_kernel(
    const float4* __restrict__ preds,
    const int4*   __restrict__ labels,
    unsigned int* __restrict__ ws,     // [0..11] counters, [12] ticket (all zeroed)
    float* __restrict__ out,
    int n4)
{
    int cnt_i[NCLS] = {0, 0, 0, 0};
    int cnt_p[NCLS] = {0, 0, 0, 0};
    int cnt_l[NCLS] = {0, 0, 0, 0};

    const int tid    = blockIdx.x * blockDim.x + threadIdx.x;
    const int stride = gridDim.x * blockDim.x;

    auto acc = [&](const float4 p, const int4 l) {
        const int ip0 = (int)p.x, ip1 = (int)p.y, ip2 = (int)p.z, ip3 = (int)p.w;
#pragma unroll
        for (int c = 0; c < NCLS; ++c) {
            const int pm0 = (ip0 == c), lm0 = (l.x == c);
            const int pm1 = (ip1 == c), lm1 = (l.y == c);
            const int pm2 = (ip2 == c), lm2 = (l.z == c);
            const int pm3 = (ip3 == c), lm3 = (l.w == c);
            cnt_i[c] += (pm0 & lm0) + (pm1 & lm1) + (pm2 & lm2) + (pm3 & lm3);
            cnt_p[c] += pm0 + pm1 + pm2 + pm3;
            cnt_l[c] += lm0 + lm1 + lm2 + lm3;
        }
    };

    int idx = tid;
    // Unroll x4: 8 independent 16B loads issued before any use.
    for (; idx + 3 * stride < n4; idx += 4 * stride) {
        const float4 p0 = preds[idx];
        const float4 p1 = preds[idx + stride];
        const float4 p2 = preds[idx + 2 * stride];
        const float4 p3 = preds[idx + 3 * stride];
        const int4   l0 = labels[idx];
        const int4   l1 = labels[idx + stride];
        const int4   l2 = labels[idx + 2 * stride];
        const int4   l3 = labels[idx + 3 * stride];
        acc(p0, l0); acc(p1, l1); acc(p2, l2); acc(p3, l3);
    }
    for (; idx < n4; idx += stride)
        acc(preds[idx], labels[idx]);

    // Wave (64-lane) shuffle reduction.
#pragma unroll
    for (int c = 0; c < NCLS; ++c) {
#pragma unroll
        for (int off = 32; off > 0; off >>= 1) {
            cnt_i[c] += __shfl_down(cnt_i[c], off);
            cnt_p[c] += __shfl_down(cnt_p[c], off);
            cnt_l[c] += __shfl_down(cnt_l[c], off);
        }
    }

    __shared__ unsigned int s[3 * NCLS];
    __shared__ int is_last;
    if (threadIdx.x < 3 * NCLS) s[threadIdx.x] = 0u;
    __syncthreads();

    if ((threadIdx.x & 63) == 0) {
#pragma unroll
        for (int c = 0; c < NCLS; ++c) {
            atomicAdd(&s[c],            (unsigned int)cnt_i[c]);
            atomicAdd(&s[NCLS + c],     (unsigned int)cnt_p[c]);
            atomicAdd(&s[2 * NCLS + c], (unsigned int)cnt_l[c]);
        }
    }
    __syncthreads();

    if (threadIdx.x < 3 * NCLS)
        atomicAdd(&ws[threadIdx.x], s[threadIdx.x]);

    // Last-block finalize (no spin; device-scope atomics).
    __threadfence();
    if (threadIdx.x == 0) {
        const unsigned t = atomicAdd(&ws[12], 1u);
        is_last = (t == gridDim.x - 1);
    }
    __syncthreads();

    if (is_last && threadIdx.x < NCLS) {
        const int c = threadIdx.x;
        const float inter = (float)atomicAdd(&ws[c], 0u);
        const float cp    = (float)atomicAdd(&ws[NCLS + c], 0u);
        const float cl    = (float)atomicAdd(&ws[2 * NCLS + c], 0u);
        const float uni   = cp + cl - inter;
        const float iou   = (uni == 0.0f) ? 1.0f : (inter / uni);
        out[c] = 1.0f - 100.0f * iou;
    }
}

extern "C" void kernel_launch(void* const* d_in, const int* in_sizes, int n_in,
                              void* d_out, int out_size, void* d_ws, size_t ws_size,
                              hipStream_t stream) {
    const float4* preds  = (const float4*)d_in[0];
    const int4*   labels = (const int4*)d_in[1];
    unsigned int* ws  = (unsigned int*)d_ws;
    float* out = (float*)d_out;

    const int n  = in_sizes[0];      // 16*1024*1024
    const int n4 = n / 4;

    // ws poisoned 0xAA every call — zero 12 counters + ticket.
    hipMemsetAsync(ws, 0, 13 * sizeof(unsigned int), stream);

    const int threads = 256;
    const int blocks  = 2048;        // 8 blocks/CU -> 32 waves/CU at 24-ish VGPR
    iou_fused_kernel<<<blocks, threads, 0, stream>>>(preds, labels, ws, out, n4);
}

// Round 3
// 152.128 us; speedup vs baseline: 2.0910x; 2.0910x over previous
//
#include <hip/hip_runtime.h>

// IoULoss, C=4 over 16x1024x1024. counters: inter[c], cnt_pred[c], cnt_label[c];
// union = cp+cl-inter. 134 MB read -> memory-service floor ~15-20 us (L3 mix).
// R3: NO global atomics, NO fences (R2 post-mortem: same-line device atomics +
// per-block __threadfence L2-invalidate storms were the cost). Each block
// stores 12 partials to a private slot; tiny second kernel reduces.

#define NCLS 4
#define NCNT (3 * NCLS)   // 12: [inter0..3 | cp0..3 | cl0..3]

__global__ __launch_bounds__(256) void iou_count_kernel(
    const float4* __restrict__ preds,
    const int4*   __restrict__ labels,
    unsigned int* __restrict__ partials,   // [NCNT][nblk], counter-major
    int n4)
{
    int cnt[NCNT] = {0,0,0,0,0,0,0,0,0,0,0,0};

    const int tid    = blockIdx.x * blockDim.x + threadIdx.x;
    const int stride = gridDim.x * blockDim.x;

    auto acc = [&](const float4 p, const int4 l) {
        const int ip0 = (int)p.x, ip1 = (int)p.y, ip2 = (int)p.z, ip3 = (int)p.w;
#pragma unroll
        for (int c = 0; c < NCLS; ++c) {
            const int pm0 = (ip0 == c), lm0 = (l.x == c);
            const int pm1 = (ip1 == c), lm1 = (l.y == c);
            const int pm2 = (ip2 == c), lm2 = (l.z == c);
            const int pm3 = (ip3 == c), lm3 = (l.w == c);
            cnt[c]            += (pm0 & lm0) + (pm1 & lm1) + (pm2 & lm2) + (pm3 & lm3);
            cnt[NCLS + c]     += pm0 + pm1 + pm2 + pm3;
            cnt[2 * NCLS + c] += lm0 + lm1 + lm2 + lm3;
        }
    };

    int idx = tid;
    // Unroll x2: 4 independent 16B loads in flight (modest VGPR cost).
    for (; idx + stride < n4; idx += 2 * stride) {
        const float4 p0 = preds[idx];
        const float4 p1 = preds[idx + stride];
        const int4   l0 = labels[idx];
        const int4   l1 = labels[idx + stride];
        acc(p0, l0);
        acc(p1, l1);
    }
    for (; idx < n4; idx += stride)
        acc(preds[idx], labels[idx]);

    // Wave (64-lane) shuffle reduction.
#pragma unroll
    for (int k = 0; k < NCNT; ++k) {
#pragma unroll
        for (int off = 32; off > 0; off >>= 1)
            cnt[k] += __shfl_down(cnt[k], off);
    }

    // Block accumulate via LDS atomics (cheap, on-CU), then 12 plain global
    // stores to this block's private slot. No contention, no fence needed:
    // kernel boundary orders the reduce kernel's reads.
    __shared__ unsigned int s[NCNT];
    if (threadIdx.x < NCNT) s[threadIdx.x] = 0u;
    __syncthreads();

    if ((threadIdx.x & 63) == 0) {
#pragma unroll
        for (int k = 0; k < NCNT; ++k)
            atomicAdd(&s[k], (unsigned int)cnt[k]);
    }
    __syncthreads();

    if (threadIdx.x < NCNT)
        partials[threadIdx.x * gridDim.x + blockIdx.x] = s[threadIdx.x];
}

// One block, 12 waves: wave w sums row w of partials; threads 0..3 finalize.
__global__ __launch_bounds__(768) void iou_reduce_kernel(
    const unsigned int* __restrict__ partials,
    float* __restrict__ out,
    int nblk)
{
    __shared__ unsigned int tot[NCNT];
    const int w    = threadIdx.x >> 6;
    const int lane = threadIdx.x & 63;

    if (w < NCNT) {
        unsigned int sum = 0;
        const unsigned int* row = partials + (size_t)w * nblk;
        for (int k = lane; k < nblk; k += 64)
            sum += row[k];
#pragma unroll
        for (int off = 32; off > 0; off >>= 1)
            sum += __shfl_down(sum, off);
        if (lane == 0) tot[w] = sum;
    }
    __syncthreads();

    if (threadIdx.x < NCLS) {
        const int c = threadIdx.x;
        const float inter = (float)tot[c];
        const float uni   = (float)tot[NCLS + c] + (float)tot[2 * NCLS + c] - (float)tot[c];
        const float iou   = (uni == 0.0f) ? 1.0f : (inter / uni);
        out[c] = 1.0f - 100.0f * iou;
    }
}

extern "C" void kernel_launch(void* const* d_in, const int* in_sizes, int n_in,
                              void* d_out, int out_size, void* d_ws, size_t ws_size,
                              hipStream_t stream) {
    const float4* preds  = (const float4*)d_in[0];
    const int4*   labels = (const int4*)d_in[1];
    unsigned int* partials = (unsigned int*)d_ws;
    float* out = (float*)d_out;

    const int n  = in_sizes[0];      // 16*1024*1024
    const int n4 = n / 4;

    // 2048 blocks = 8 blocks/CU -> 32 waves/CU; clamp to workspace capacity.
    int nblk = 2048;
    const int cap = (int)(ws_size / (NCNT * sizeof(unsigned int)));
    if (cap < nblk) nblk = cap;
    if (nblk < 1) nblk = 1;

    iou_count_kernel<<<nblk, 256, 0, stream>>>(preds, labels, partials, n4);
    iou_reduce_kernel<<<1, 768, 0, stream>>>(partials, out, nblk);
}

// Round 4
// 144.369 us; speedup vs baseline: 2.2034x; 1.0537x over previous
//
#include <hip/hip_runtime.h>

// IoULoss, C=4 over 16x1024x1024 preds(float,int-valued)/labels(int).
// inter[c], cnt_pred[c], cnt_label[c]; union = cp+cl-inter.
// R4 theory: R1/R3 pinned at 46us = 2.9 TB/s effective regardless of grid/
// unroll => instruction-issue bound (~32 VALU/elem from per-class cmp+cndmask).
// Fix: packed-byte histogram — acc += 1<<(8*v) — ~10 VALU/elem, no class loop.

#define NCLS 4
#define NCNT (3 * NCLS)   // final counters: [inter0..3 | cp0..3 | cl0..3]

__global__ __launch_bounds__(256) void iou_count_kernel(
    const float4* __restrict__ preds,
    const int4*   __restrict__ labels,
    unsigned int* __restrict__ partials,   // [NCNT][nblk], counter-major
    int n4)
{
    // Packed 8-bit class histograms: field c = byte c. Max 64 elems/thread < 255.
    unsigned int acc_i = 0, acc_p = 0, acc_l = 0;

    const int tid    = blockIdx.x * blockDim.x + threadIdx.x;
    const int stride = gridDim.x * blockDim.x;

    auto proc = [&](float pf, int lv) {
        const int      ip = (int)pf;
        const unsigned tp = 1u << (ip << 3);
        const unsigned tl = 1u << (lv << 3);
        acc_p += tp;
        acc_l += tl;
        acc_i += (ip == lv) ? tl : 0u;
    };
    auto acc4 = [&](const float4 p, const int4 l) {
        proc(p.x, l.x); proc(p.y, l.y); proc(p.z, l.z); proc(p.w, l.w);
    };

    int idx = tid;
    for (; idx + stride < n4; idx += 2 * stride) {
        const float4 p0 = preds[idx];
        const float4 p1 = preds[idx + stride];
        const int4   l0 = labels[idx];
        const int4   l1 = labels[idx + stride];
        acc4(p0, l0);
        acc4(p1, l1);
    }
    for (; idx < n4; idx += stride)
        acc4(preds[idx], labels[idx]);

    // Split packed-8 into packed-16 pairs (classes {0,2} / {1,3}) so 64-lane
    // sums fit in 16 bits (64*64=4096 < 65536). 6 values instead of 12.
    unsigned pk[6];
    pk[0] = acc_i & 0x00FF00FFu; pk[1] = (acc_i >> 8) & 0x00FF00FFu;
    pk[2] = acc_p & 0x00FF00FFu; pk[3] = (acc_p >> 8) & 0x00FF00FFu;
    pk[4] = acc_l & 0x00FF00FFu; pk[5] = (acc_l >> 8) & 0x00FF00FFu;

#pragma unroll
    for (int k = 0; k < 6; ++k) {
#pragma unroll
        for (int off = 32; off > 0; off >>= 1)
            pk[k] += __shfl_down(pk[k], off);
    }

    // Cross-wave combine in LDS (4 waves). Packed sums: 4096*4 < 65536, safe.
    __shared__ unsigned int s[4][6];
    const int wave = threadIdx.x >> 6;
    if ((threadIdx.x & 63) == 0) {
#pragma unroll
        for (int k = 0; k < 6; ++k) s[wave][k] = pk[k];
    }
    __syncthreads();

    if (threadIdx.x < 6) {
        const int k = threadIdx.x;
        const unsigned tot = s[0][k] + s[1][k] + s[2][k] + s[3][k];
        // pk index k -> counter pair: group g=k/2 (0=inter,1=cp,2=cl),
        // parity r=k&1: low16 = class r, high16 = class r+2.
        const int g = k >> 1, r = k & 1;
        partials[(g * NCLS + r)     * gridDim.x + blockIdx.x] = tot & 0xFFFFu;
        partials[(g * NCLS + r + 2) * gridDim.x + blockIdx.x] = tot >> 16;
    }
}

// One block, 12 waves: wave w sums counter row w; threads 0..3 finalize.
__global__ __launch_bounds__(768) void iou_reduce_kernel(
    const unsigned int* __restrict__ partials,
    float* __restrict__ out,
    int nblk)
{
    __shared__ unsigned int tot[NCNT];
    const int w    = threadIdx.x >> 6;
    const int lane = threadIdx.x & 63;

    if (w < NCNT) {
        unsigned int sum = 0;
        const unsigned int* row = partials + (size_t)w * nblk;
        for (int k = lane; k < nblk; k += 64)
            sum += row[k];
#pragma unroll
        for (int off = 32; off > 0; off >>= 1)
            sum += __shfl_down(sum, off);
        if (lane == 0) tot[w] = sum;
    }
    __syncthreads();

    if (threadIdx.x < NCLS) {
        const int c = threadIdx.x;
        const float inter = (float)tot[c];
        const float uni   = (float)tot[NCLS + c] + (float)tot[2 * NCLS + c]
                            - (float)tot[c];
        const float iou   = (uni == 0.0f) ? 1.0f : (inter / uni);
        out[c] = 1.0f - 100.0f * iou;
    }
}

extern "C" void kernel_launch(void* const* d_in, const int* in_sizes, int n_in,
                              void* d_out, int out_size, void* d_ws, size_t ws_size,
                              hipStream_t stream) {
    const float4* preds  = (const float4*)d_in[0];
    const int4*   labels = (const int4*)d_in[1];
    unsigned int* partials = (unsigned int*)d_ws;
    float* out = (float*)d_out;

    const int n  = in_sizes[0];      // 16*1024*1024
    const int n4 = n / 4;

    // 1024 blocks: 64 elems/thread keeps 8-bit fields safe (<255) and
    // amortizes the reduction tail; R1 vs R3 showed 1024 vs 2048 is neutral.
    int nblk = 1024;
    const int cap = (int)(ws_size / (NCNT * sizeof(unsigned int)));
    if (cap < nblk) nblk = cap;
    if (nblk < 1) nblk = 1;

    iou_count_kernel<<<nblk, 256, 0, stream>>>(preds, labels, partials, n4);
    iou_reduce_kernel<<<1, 768, 0, stream>>>(partials, out, nblk);
}

// Round 6
// 143.656 us; speedup vs baseline: 2.2144x; 1.0050x over previous
//
#include <hip/hip_runtime.h>

// IoULoss, C=4 over 16x1024x1024 preds(float,int-valued)/labels(int).
// inter[c], cnt_pred[c], cnt_label[c]; union = cp+cl-inter.
// R6 = R5 with compile fix: __builtin_nontemporal_load requires native clang
// ext_vector_type, not HIP_vector_type (float4/int4). Theory unchanged:
// 42-48us invariant (~3.2 TB/s) across VALU/grid/unroll changes => per-CU
// memory-path ceiling; try nt streaming loads + 8-deep load pipelining.

#define NCLS 4
#define NCNT (3 * NCLS)   // [inter0..3 | cp0..3 | cl0..3]

typedef float vf4 __attribute__((ext_vector_type(4)));
typedef int   vi4 __attribute__((ext_vector_type(4)));

__global__ __launch_bounds__(256) void iou_count_kernel(
    const vf4* __restrict__ preds,
    const vi4* __restrict__ labels,
    unsigned int* __restrict__ partials,   // [NCNT][nblk], counter-major
    int n4)
{
    unsigned int acc_i = 0, acc_p = 0, acc_l = 0;

    const int tid    = blockIdx.x * blockDim.x + threadIdx.x;
    const int stride = gridDim.x * blockDim.x;

    auto proc = [&](float pf, int lv) {
        const int      ip = (int)pf;
        const unsigned tp = 1u << (ip << 3);
        const unsigned tl = 1u << (lv << 3);
        acc_p += tp;
        acc_l += tl;
        acc_i += (ip == lv) ? tl : 0u;
    };
    auto acc4 = [&](const vf4 p, const vi4 l) {
        proc(p.x, l.x); proc(p.y, l.y); proc(p.z, l.z); proc(p.w, l.w);
    };

    int idx = tid;
    // Unroll x4 with nontemporal loads: 8 independent 16B streams in flight.
    for (; idx + 3 * stride < n4; idx += 4 * stride) {
        const vf4 p0 = __builtin_nontemporal_load(&preds[idx]);
        const vf4 p1 = __builtin_nontemporal_load(&preds[idx + stride]);
        const vf4 p2 = __builtin_nontemporal_load(&preds[idx + 2 * stride]);
        const vf4 p3 = __builtin_nontemporal_load(&preds[idx + 3 * stride]);
        const vi4 l0 = __builtin_nontemporal_load(&labels[idx]);
        const vi4 l1 = __builtin_nontemporal_load(&labels[idx + stride]);
        const vi4 l2 = __builtin_nontemporal_load(&labels[idx + 2 * stride]);
        const vi4 l3 = __builtin_nontemporal_load(&labels[idx + 3 * stride]);
        acc4(p0, l0); acc4(p1, l1); acc4(p2, l2); acc4(p3, l3);
    }
    for (; idx < n4; idx += stride)
        acc4(__builtin_nontemporal_load(&preds[idx]),
             __builtin_nontemporal_load(&labels[idx]));

    // Split packed-8 into packed-16 pairs (classes {0,2}/{1,3}).
    unsigned pk[6];
    pk[0] = acc_i & 0x00FF00FFu; pk[1] = (acc_i >> 8) & 0x00FF00FFu;
    pk[2] = acc_p & 0x00FF00FFu; pk[3] = (acc_p >> 8) & 0x00FF00FFu;
    pk[4] = acc_l & 0x00FF00FFu; pk[5] = (acc_l >> 8) & 0x00FF00FFu;

#pragma unroll
    for (int k = 0; k < 6; ++k) {
#pragma unroll
        for (int off = 32; off > 0; off >>= 1)
            pk[k] += __shfl_down(pk[k], off);
    }

    __shared__ unsigned int s[4][6];
    const int wave = threadIdx.x >> 6;
    if ((threadIdx.x & 63) == 0) {
#pragma unroll
        for (int k = 0; k < 6; ++k) s[wave][k] = pk[k];
    }
    __syncthreads();

    if (threadIdx.x < 6) {
        const int k = threadIdx.x;
        const unsigned tot = s[0][k] + s[1][k] + s[2][k] + s[3][k];
        const int g = k >> 1, r = k & 1;   // group, low-class parity
        partials[(g * NCLS + r)     * gridDim.x + blockIdx.x] = tot & 0xFFFFu;
        partials[(g * NCLS + r + 2) * gridDim.x + blockIdx.x] = tot >> 16;
    }
}

// One block, 12 waves: wave w sums counter row w; threads 0..3 finalize.
__global__ __launch_bounds__(768) void iou_reduce_kernel(
    const unsigned int* __restrict__ partials,
    float* __restrict__ out,
    int nblk)
{
    __shared__ unsigned int tot[NCNT];
    const int w    = threadIdx.x >> 6;
    const int lane = threadIdx.x & 63;

    if (w < NCNT) {
        unsigned int sum = 0;
        const unsigned int* row = partials + (size_t)w * nblk;
        for (int k = lane; k < nblk; k += 64)
            sum += row[k];
#pragma unroll
        for (int off = 32; off > 0; off >>= 1)
            sum += __shfl_down(sum, off);
        if (lane == 0) tot[w] = sum;
    }
    __syncthreads();

    if (threadIdx.x < NCLS) {
        const int c = threadIdx.x;
        const float inter = (float)tot[c];
        const float uni   = (float)tot[NCLS + c] + (float)tot[2 * NCLS + c]
                            - (float)tot[c];
        const float iou   = (uni == 0.0f) ? 1.0f : (inter / uni);
        out[c] = 1.0f - 100.0f * iou;
    }
}

extern "C" void kernel_launch(void* const* d_in, const int* in_sizes, int n_in,
                              void* d_out, int out_size, void* d_ws, size_t ws_size,
                              hipStream_t stream) {
    const vf4* preds  = (const vf4*)d_in[0];
    const vi4* labels = (const vi4*)d_in[1];
    unsigned int* partials = (unsigned int*)d_ws;
    float* out = (float*)d_out;

    const int n  = in_sizes[0];      // 16*1024*1024
    const int n4 = n / 4;

    int nblk = 2048;
    const int cap = (int)(ws_size / (NCNT * sizeof(unsigned int)));
    if (cap < nblk) nblk = cap;
    if (nblk < 1) nblk = 1;

    iou_count_kernel<<<nblk, 256, 0, stream>>>(preds, labels, partials, n4);
    iou_reduce_kernel<<<1, 768, 0, stream>>>(partials, out, nblk);
}